// Round 5
// baseline (316.506 us; speedup 1.0000x reference)
//
#include <hip/hip_runtime.h>

// Problem constants (B=16, C=128, H=W=64, N=4096, M=256, K=9, OUT=128)
#define NB   16
#define NC   128
#define NN   4096
#define NM   256
#define NK   9
#define NO   128

#define DELTA 0.0078125f   // candidate margin: ~4x worst-case fma-vs-np key bound

// round(linspace(0, 63, 16))
__device__ __constant__ int d_grid16[16] = {0,4,8,13,17,21,25,29,34,38,42,46,50,55,59,63};

// ---------------------------------------------------------------------------
// K0: transpose w (O,C,K) -> Wr (C,K,O)
__global__ __launch_bounds__(256) void k_wr(const float* __restrict__ w,
                                            float* __restrict__ Wr) {
    int f = blockIdx.x * 256 + threadIdx.x;         // f < 147456
    int o = f & 127;
    int k = (f >> 7) % 9;
    int c = f / 1152;
    Wr[f] = w[o * 1152 + c * 9 + k];
}

// ---------------------------------------------------------------------------
// K1: gather sample features xs[b][c][m] = x[b][c][pix(m)]
__global__ __launch_bounds__(256) void k_gather(const float* __restrict__ x,
                                                float* __restrict__ xs) {
    int bc = blockIdx.x;                            // b*128 + c
    int m  = threadIdx.x;                           // 0..255
    int pix = d_grid16[m >> 4] * 64 + d_grid16[m & 15];
    xs[bc * NM + m] = x[bc * NN + pix];
}

// ---------------------------------------------------------------------------
// K1t: transpose xs (B,C,M) -> xs_T (B,M,C), LDS-tiled, coalesced both sides
__global__ __launch_bounds__(256) void k_xt(const float* __restrict__ xs,
                                            float* __restrict__ xsT) {
    __shared__ float tile[16 * 260];
    int c0 = blockIdx.x * 16, b = blockIdx.y;
    int t = threadIdx.x;
    #pragma unroll
    for (int it = 0; it < 4; ++it) {                // 1024 float4
        int f4 = it * 256 + t;
        int cc = f4 >> 6, mm4 = (f4 & 63) * 4;
        *(float4*)&tile[cc * 260 + mm4] =
            *(const float4*)&xs[((size_t)b * NC + c0 + cc) * NM + mm4];
    }
    __syncthreads();
    int m = t;                                      // 0..255
    #pragma unroll
    for (int e = 0; e < 4; ++e) {
        float4 v;
        v.x = tile[(4 * e + 0) * 260 + m];
        v.y = tile[(4 * e + 1) * 260 + m];
        v.z = tile[(4 * e + 2) * 260 + m];
        v.w = tile[(4 * e + 3) * 260 + m];
        *(float4*)&xsT[((size_t)b * NM + m) * NC + c0 + 4 * e] = v;
    }
}

// ---------------------------------------------------------------------------
// K1b: m2[b][m] = sum_c xs^2 -- np-bit-exact: sequential c, mul+add (no fma)
__global__ __launch_bounds__(64) void k_m2(const float* __restrict__ xsT,
                                           float* __restrict__ m2) {
    #pragma clang fp contract(off)
    int f = blockIdx.x * 64 + threadIdx.x;          // < 4096 == b*256+m
    const float* p = xsT + (size_t)f * NC;
    float a = 0.f;
    for (int c4 = 0; c4 < 32; ++c4) {
        float4 v = *(const float4*)&p[4 * c4];
        a = __fadd_rn(a, __fmul_rn(v.x, v.x));
        a = __fadd_rn(a, __fmul_rn(v.y, v.y));
        a = __fadd_rn(a, __fmul_rn(v.z, v.z));
        a = __fadd_rn(a, __fmul_rn(v.w, v.w));
    }
    m2[f] = a;
}

// ---------------------------------------------------------------------------
// K2: G[b][m][k][o] = sum_c xs[b][c][m] * Wr[c][k][o]   (fp32 fma - output path)
__global__ __launch_bounds__(256) void k_g(const float* __restrict__ xs,
                                           const float* __restrict__ Wr,
                                           float* __restrict__ G) {
    __shared__ float xsl[64 * 64];
    __shared__ float wl[64 * 128];
    int kk = blockIdx.x, mt = blockIdx.y, b = blockIdx.z;
    int t = threadIdx.x;
    int to = t & 31, tmm = t >> 5;
    float acc[8][4] = {};
    for (int c0 = 0; c0 < NC; c0 += 64) {
        __syncthreads();
        #pragma unroll
        for (int it = 0; it < 16; ++it) {
            int f = it * 256 + t;
            int cc = f >> 6, mm = f & 63;
            xsl[f] = xs[((size_t)b * NC + c0 + cc) * NM + mt * 64 + mm];
        }
        #pragma unroll
        for (int it = 0; it < 32; ++it) {
            int f = it * 256 + t;
            int cc = f >> 7, o = f & 127;
            wl[f] = Wr[(size_t)(c0 + cc) * 1152 + kk * 128 + o];
        }
        __syncthreads();
        for (int cc = 0; cc < 64; ++cc) {
            const float4 a0 = *(const float4*)&xsl[cc * 64 + tmm * 8];
            const float4 a1 = *(const float4*)&xsl[cc * 64 + tmm * 8 + 4];
            float av[8] = {a0.x, a0.y, a0.z, a0.w, a1.x, a1.y, a1.z, a1.w};
            float2 w0 = *(const float2*)&wl[cc * 128 + 2 * to];
            float2 w1 = *(const float2*)&wl[cc * 128 + 64 + 2 * to];
            float wv[4] = {w0.x, w0.y, w1.x, w1.y};
            #pragma unroll
            for (int i = 0; i < 8; ++i)
                #pragma unroll
                for (int j = 0; j < 4; ++j)
                    acc[i][j] = fmaf(av[i], wv[j], acc[i][j]);
        }
    }
    #pragma unroll
    for (int i = 0; i < 8; ++i) {
        size_t base = (((size_t)(b * NM + mt * 64 + tmm * 8 + i) * NK + kk) << 7);
        *(float2*)&G[base + 2 * to]      = make_float2(acc[i][0], acc[i][1]);
        *(float2*)&G[base + 64 + 2 * to] = make_float2(acc[i][2], acc[i][3]);
    }
}

// ---------------------------------------------------------------------------
// K3 pass 1: FMA dots + approx top-9 -> threshold -> candidates (<=16/token).
// grid (64 tiles, 16 b), 256 thr; tile = 64 tokens x 256 samples.
// Per thread: 8 tokens x 8 samples; all LDS reads are b128.
__device__ inline unsigned long long shfl_xor_u64(unsigned long long v, int m) {
    int lo = __shfl_xor((int)(v & 0xFFFFFFFFull), m, 64);
    int hi = __shfl_xor((int)(v >> 32), m, 64);
    return ((unsigned long long)(unsigned)hi << 32) | (unsigned)lo;
}

__global__ __launch_bounds__(256) void k_sel(const float* __restrict__ x,
                                             const float* __restrict__ xs,
                                             const float* __restrict__ m2,
                                             unsigned short* __restrict__ cand) {
    // sm: x1 tile [0,2048): [cc][nn] 32x64 ; xs tile [2048,10240): [cc][m] 32x256
    // phases B/C reuse sm as float keys [32][260] = 8320 <= 10240 (two 32-token halves)
    __shared__ float sm[10240];
    __shared__ float m2l[256];
    __shared__ int   cntl[64];
    int b = blockIdx.y, n0 = blockIdx.x * 64;
    int t = threadIdx.x;
    int tm = t & 31, tn = t >> 5;     // tm: samples 4tm..4tm+3 & 128+4tm..; tn: tokens tn*8..tn*8+7
    m2l[t] = m2[b * NM + t];
    if (t < 64) cntl[t] = 0;
    float acc[8][8];
    #pragma unroll
    for (int i = 0; i < 8; ++i)
        #pragma unroll
        for (int j = 0; j < 8; ++j) acc[i][j] = 0.f;

    for (int c0 = 0; c0 < NC; c0 += 32) {
        __syncthreads();
        #pragma unroll
        for (int it = 0; it < 2; ++it) {            // x1: 512 float4
            int f4 = it * 256 + t;
            int cc = f4 >> 4, nn4 = (f4 & 15) * 4;
            *(float4*)&sm[cc * 64 + nn4] =
                *(const float4*)&x[((size_t)b * NC + c0 + cc) * NN + n0 + nn4];
        }
        #pragma unroll
        for (int it = 0; it < 8; ++it) {            // xs: 2048 float4
            int f4 = it * 256 + t;
            int cc = f4 >> 6, mm4 = (f4 & 63) * 4;
            *(float4*)&sm[2048 + cc * 256 + mm4] =
                *(const float4*)&xs[((size_t)b * NC + c0 + cc) * NM + mm4];
        }
        __syncthreads();
        for (int cc = 0; cc < 32; ++cc) {
            const float4 a0 = *(const float4*)&sm[cc * 64 + tn * 8];
            const float4 a1 = *(const float4*)&sm[cc * 64 + tn * 8 + 4];
            float av[8] = {a0.x, a0.y, a0.z, a0.w, a1.x, a1.y, a1.z, a1.w};
            const float4 s0 = *(const float4*)&sm[2048 + cc * 256 + 4 * tm];
            const float4 s1 = *(const float4*)&sm[2048 + cc * 256 + 128 + 4 * tm];
            float sv[8] = {s0.x, s0.y, s0.z, s0.w, s1.x, s1.y, s1.z, s1.w};
            #pragma unroll
            for (int i = 0; i < 8; ++i)
                #pragma unroll
                for (int j = 0; j < 8; ++j)
                    acc[i][j] = fmaf(av[i], sv[j], acc[i][j]);
        }
    }
    // preload m2 for owned samples
    float m2v[8];
    #pragma unroll
    for (int j = 0; j < 8; ++j) m2v[j] = m2l[(j < 4 ? 4 * tm + j : 128 + 4 * tm + j - 4)];
    float* keysl = sm;
    int h0 = tn >> 2;                 // which half this thread's tokens belong to
    __syncthreads();

    #pragma unroll
    for (int h = 0; h < 2; ++h) {
        // ---- phase B: write keys (m2 - 2*dot) for tokens in half h ----
        if (h0 == h) {
            int rbase = (tn & 3) * 8;
            #pragma unroll
            for (int i = 0; i < 8; ++i) {
                int r = rbase + i;
                float4 k0, k1;
                k0.x = fmaf(-2.f, acc[i][0], m2v[0]);
                k0.y = fmaf(-2.f, acc[i][1], m2v[1]);
                k0.z = fmaf(-2.f, acc[i][2], m2v[2]);
                k0.w = fmaf(-2.f, acc[i][3], m2v[3]);
                k1.x = fmaf(-2.f, acc[i][4], m2v[4]);
                k1.y = fmaf(-2.f, acc[i][5], m2v[5]);
                k1.z = fmaf(-2.f, acc[i][6], m2v[6]);
                k1.w = fmaf(-2.f, acc[i][7], m2v[7]);
                *(float4*)&keysl[r * 260 + 4 * tm]       = k0;
                *(float4*)&keysl[r * 260 + 128 + 4 * tm] = k1;
            }
        }
        __syncthreads();
        // ---- phase C: approx top-9 (8 lanes/token) -> theta -> collect ----
        {
            int r = t >> 3, q = t & 7;
            unsigned long long bk[9];
            #pragma unroll
            for (int j = 0; j < 9; ++j) bk[j] = ~0ull;
            for (int i = 0; i < 32; ++i) {
                int m = q + 8 * i;
                unsigned u = __float_as_uint(keysl[r * 260 + m]);
                u = (u & 0x80000000u) ? ~u : (u | 0x80000000u);
                unsigned long long v = ((unsigned long long)u << 32) | (unsigned)m;
                if (v < bk[8]) {
                    #pragma unroll
                    for (int j = 0; j < 9; ++j) {
                        unsigned long long t0 = bk[j];
                        bool c = v < t0;
                        bk[j] = c ? v : t0;
                        v     = c ? t0 : v;
                    }
                }
            }
            #pragma unroll
            for (int rr = 1; rr <= 4; rr <<= 1) {
                unsigned long long pv[9];
                #pragma unroll
                for (int j = 0; j < 9; ++j) pv[j] = shfl_xor_u64(bk[j], rr);
                #pragma unroll
                for (int j = 0; j < 9; ++j) {
                    unsigned long long v = pv[j];
                    if (v >= bk[8]) break;
                    #pragma unroll
                    for (int jj = 0; jj < 9; ++jj) {
                        unsigned long long t0 = bk[jj];
                        bool c = v < t0;
                        bk[jj] = c ? v : t0;
                        v      = c ? t0 : v;
                    }
                }
            }
            unsigned u9 = (unsigned)(bk[8] >> 32);
            u9 = (u9 & 0x80000000u) ? (u9 & 0x7FFFFFFFu) : ~u9;
            float theta = __uint_as_float(u9) + DELTA;
            int tok = 32 * h + r;
            size_t tokbase = (size_t)(b * NN + n0 + tok) * 16;
            for (int i = 0; i < 32; ++i) {
                int m = q + 8 * i;
                if (keysl[r * 260 + m] <= theta) {
                    int pos = atomicAdd(&cntl[tok], 1);
                    if (pos < 16) cand[tokbase + pos] = (unsigned short)m;
                }
            }
            __syncthreads();
            if (q == 0) {
                int c = cntl[tok]; if (c > 16) c = 16;
                for (int s = c; s < 16; ++s) cand[tokbase + s] = 0xFFFFu;
            }
        }
        __syncthreads();
    }
}

// ---------------------------------------------------------------------------
// K3 pass 2: np-bit-exact re-rank of <=16 candidates/token, reading xs_T.
// grid (64, 16), 256 thr; 64 tokens/block, 4 lanes/token, 4 slots/lane.
__global__ __launch_bounds__(256) void k_ref(const float* __restrict__ x,
                                             const float* __restrict__ xsT,
                                             const float* __restrict__ m2,
                                             const unsigned short* __restrict__ cand,
                                             int* __restrict__ idx) {
    #pragma clang fp contract(off)
    __shared__ float x1l[128 * 64];   // [c][r] 32 KB
    __shared__ float m2l[256];
    __shared__ unsigned long long pairs[64 * 16];   // 8 KB
    int b = blockIdx.y, n0 = blockIdx.x * 64;
    int t = threadIdx.x;
    m2l[t] = m2[b * NM + t];
    #pragma unroll
    for (int s = 0; s < 4; ++s) pairs[t * 4 + s] = ~0ull;
    #pragma unroll
    for (int it = 0; it < 8; ++it) {                // 2048 float4
        int f4 = it * 256 + t;
        int cc = f4 >> 4, nn4 = (f4 & 15) * 4;
        *(float4*)&x1l[cc * 64 + nn4] =
            *(const float4*)&x[((size_t)b * NC + cc) * NN + n0 + nn4];
    }
    __syncthreads();
    int r = t >> 2, q = t & 3;
    int n = n0 + r;
    size_t tokbase = (size_t)(b * NN + n) * 16;
    // np-exact n2 (sequential c)
    float n2 = 0.f;
    #pragma unroll 4
    for (int c = 0; c < NC; ++c) { float v = x1l[c * 64 + r]; n2 = __fadd_rn(n2, __fmul_rn(v, v)); }
    int   mym[4];
    #pragma unroll
    for (int s = 0; s < 4; ++s) {
        int m = cand[tokbase + q + 4 * s];
        mym[s] = m;
        if (m != 0xFFFF) {
            const float* xt = xsT + ((size_t)b * NM + m) * NC;
            float dot = 0.f;
            for (int c4 = 0; c4 < 32; ++c4) {       // sequential within float4: np order
                float4 sv = *(const float4*)&xt[4 * c4];
                dot = __fadd_rn(dot, __fmul_rn(x1l[(4 * c4 + 0) * 64 + r], sv.x));
                dot = __fadd_rn(dot, __fmul_rn(x1l[(4 * c4 + 1) * 64 + r], sv.y));
                dot = __fadd_rn(dot, __fmul_rn(x1l[(4 * c4 + 2) * 64 + r], sv.z));
                dot = __fadd_rn(dot, __fmul_rn(x1l[(4 * c4 + 3) * 64 + r], sv.w));
            }
            float key = __fsub_rn(__fadd_rn(n2, m2l[m]), __fmul_rn(2.f, dot));
            unsigned u = __float_as_uint(key);
            u = (u & 0x80000000u) ? ~u : (u | 0x80000000u);
            pairs[r * 16 + q * 4 + s] = ((unsigned long long)u << 32) | (unsigned)m;
        }
    }
    __syncthreads();
    unsigned long long pl[16];
    #pragma unroll
    for (int l = 0; l < 16; ++l) pl[l] = pairs[r * 16 + l];
    size_t obase = (size_t)(b * NN + n) * NK;
    #pragma unroll
    for (int s = 0; s < 4; ++s) {
        if (mym[s] != 0xFFFF) {
            unsigned long long p = pairs[r * 16 + q * 4 + s];
            int rank = 0;
            #pragma unroll
            for (int l = 0; l < 16; ++l) rank += (pl[l] < p);
            if (rank < 9) idx[obase + rank] = mym[s];
        }
    }
}

// ---------------------------------------------------------------------------
// K4: out[b][o][n] = bias[o] + sum_k G[b][idx[b,n,k]][k][o]
__global__ __launch_bounds__(256) void k_out(const float* __restrict__ G,
                                             const int* __restrict__ idx,
                                             const float* __restrict__ bias,
                                             float* __restrict__ out) {
    __shared__ float S[64 * 129];
    __shared__ int   idxl[576];
    __shared__ float biasl[128];
    int b = blockIdx.y, n0 = blockIdx.x * 64;
    int t = threadIdx.x;
    if (t < 128) biasl[t] = bias[t];
    for (int f = t; f < 576; f += 256) idxl[f] = idx[(size_t)(b * NN + n0) * NK + f];
    __syncthreads();
    int o = t & 127, half = t >> 7;
    for (int p = 0; p < 32; ++p) {
        int n = p * 2 + half;
        float a = biasl[o];
        #pragma unroll
        for (int k = 0; k < 9; ++k) {
            int m = idxl[n * 9 + k];
            a += G[(((size_t)(b * NM + m)) * NK + k) * 128 + o];
        }
        S[n * 129 + o] = a;
    }
    __syncthreads();
    int nn = t & 63, ob = t >> 6;
    for (int p = 0; p < 32; ++p) {
        int o2 = p * 4 + ob;
        out[((size_t)(b * NO + o2)) * NN + n0 + nn] = S[nn * 129 + o2];
    }
}

// ---------------------------------------------------------------------------
extern "C" void kernel_launch(void* const* d_in, const int* in_sizes, int n_in,
                              void* d_out, int out_size, void* d_ws, size_t ws_size,
                              hipStream_t stream) {
    const float* x    = (const float*)d_in[0];   // (16,128,64,64)
    const float* w    = (const float*)d_in[1];   // (128,128,9)
    const float* bias = (const float*)d_in[2];   // (128,)
    float* out = (float*)d_out;

    float* ws   = (float*)d_ws;
    float* m2   = ws;                        // 4096
    float* xs   = ws + 4096;                 // 524288
    float* xsT  = ws + 528384;               // 524288
    float* Wr   = ws + 1052672;              // 147456
    float* G    = ws + 1200128;              // 4718592
    int*   idx  = (int*)(ws + 5918720);      // 589824
    unsigned short* cand = (unsigned short*)(ws + 6508544);  // 16*4096*16 u16 (~28 MB total)

    k_wr    <<<dim3(576),       dim3(256), 0, stream>>>(w, Wr);
    k_gather<<<dim3(2048),      dim3(256), 0, stream>>>(x, xs);
    k_xt    <<<dim3(8, 16),     dim3(256), 0, stream>>>(xs, xsT);
    k_m2    <<<dim3(64),        dim3(64),  0, stream>>>(xsT, m2);
    k_g     <<<dim3(9, 4, 16),  dim3(256), 0, stream>>>(xs, Wr, G);
    k_sel   <<<dim3(64, 16),    dim3(256), 0, stream>>>(x, xs, m2, cand);
    k_ref   <<<dim3(64, 16),    dim3(256), 0, stream>>>(x, xsT, m2, cand, idx);
    k_out   <<<dim3(64, 16),    dim3(256), 0, stream>>>(G, idx, bias, out);
}

// Round 6
// 272.579 us; speedup vs baseline: 1.1612x; 1.1612x over previous
//
#include <hip/hip_runtime.h>

// Problem constants (B=16, C=128, H=W=64, N=4096, M=256, K=9, OUT=128)
#define NB   16
#define NC   128
#define NN   4096
#define NM   256
#define NK   9
#define NO   128

#define DELTA 0.03f   // covers split-bf16 + fp32-accum key error (<=~1e-3) with big margin

typedef __attribute__((ext_vector_type(8))) short bf16x8;
typedef __attribute__((ext_vector_type(4))) float f32x4;

__device__ __constant__ int d_grid16[16] = {0,4,8,13,17,21,25,29,34,38,42,46,50,55,59,63};

__device__ inline unsigned short bf16_rne(float v) {
    unsigned u = __float_as_uint(v);
    return (unsigned short)((u + 0x7FFFu + ((u >> 16) & 1u)) >> 16);
}

// ---------------------------------------------------------------------------
// K0: transpose w (O,C,K) -> Wr (C,K,O)
__global__ __launch_bounds__(256) void k_wr(const float* __restrict__ w,
                                            float* __restrict__ Wr) {
    int f = blockIdx.x * 256 + threadIdx.x;         // f < 147456
    int o = f & 127;
    int k = (f >> 7) % 9;
    int c = f / 1152;
    Wr[f] = w[o * 1152 + c * 9 + k];
}

// ---------------------------------------------------------------------------
// K1: gather sample features xs[b][c][m] = x[b][c][pix(m)]
__global__ __launch_bounds__(256) void k_gather(const float* __restrict__ x,
                                                float* __restrict__ xs) {
    int bc = blockIdx.x;                            // b*128 + c
    int m  = threadIdx.x;                           // 0..255
    int pix = d_grid16[m >> 4] * 64 + d_grid16[m & 15];
    xs[bc * NM + m] = x[bc * NN + pix];
}

// ---------------------------------------------------------------------------
// K1t: transpose xs (B,C,M) -> xsT f32 (B,M,C) + split bf16 planes (B,M,C)
__global__ __launch_bounds__(256) void k_xt(const float* __restrict__ xs,
                                            float* __restrict__ xsT,
                                            unsigned short* __restrict__ xsTh,
                                            unsigned short* __restrict__ xsTl) {
    __shared__ float tile[16 * 260];
    int c0 = blockIdx.x * 16, b = blockIdx.y;
    int t = threadIdx.x;
    #pragma unroll
    for (int it = 0; it < 4; ++it) {                // 1024 float4
        int f4 = it * 256 + t;
        int cc = f4 >> 6, mm4 = (f4 & 63) * 4;
        *(float4*)&tile[cc * 260 + mm4] =
            *(const float4*)&xs[((size_t)b * NC + c0 + cc) * NM + mm4];
    }
    __syncthreads();
    int m = t;                                      // 0..255
    #pragma unroll
    for (int e = 0; e < 4; ++e) {
        float4 v;
        v.x = tile[(4 * e + 0) * 260 + m];
        v.y = tile[(4 * e + 1) * 260 + m];
        v.z = tile[(4 * e + 2) * 260 + m];
        v.w = tile[(4 * e + 3) * 260 + m];
        size_t base = ((size_t)b * NM + m) * NC + c0 + 4 * e;
        *(float4*)&xsT[base] = v;
        ushort4 hv, lv;
        float fv[4] = {v.x, v.y, v.z, v.w};
        unsigned short h4[4], l4[4];
        #pragma unroll
        for (int e2 = 0; e2 < 4; ++e2) {
            unsigned short h = bf16_rne(fv[e2]);
            float hf = __uint_as_float(((unsigned)h) << 16);
            h4[e2] = h;
            l4[e2] = bf16_rne(fv[e2] - hf);
        }
        hv.x = h4[0]; hv.y = h4[1]; hv.z = h4[2]; hv.w = h4[3];
        lv.x = l4[0]; lv.y = l4[1]; lv.z = l4[2]; lv.w = l4[3];
        *(ushort4*)&xsTh[base] = hv;
        *(ushort4*)&xsTl[base] = lv;
    }
}

// ---------------------------------------------------------------------------
// K1b: m2[b][m] = sum_c xs^2 -- np-bit-exact: sequential c, mul+add (no fma)
__global__ __launch_bounds__(64) void k_m2(const float* __restrict__ xsT,
                                           float* __restrict__ m2) {
    #pragma clang fp contract(off)
    int f = blockIdx.x * 64 + threadIdx.x;          // < 4096 == b*256+m
    const float* p = xsT + (size_t)f * NC;
    float a = 0.f;
    for (int c4 = 0; c4 < 32; ++c4) {
        float4 v = *(const float4*)&p[4 * c4];
        a = __fadd_rn(a, __fmul_rn(v.x, v.x));
        a = __fadd_rn(a, __fmul_rn(v.y, v.y));
        a = __fadd_rn(a, __fmul_rn(v.z, v.z));
        a = __fadd_rn(a, __fmul_rn(v.w, v.w));
    }
    m2[f] = a;
}

// ---------------------------------------------------------------------------
// K2: G[b][m][k][o] = sum_c xs[b][c][m] * Wr[c][k][o]   (fp32 fma - output path)
__global__ __launch_bounds__(256) void k_g(const float* __restrict__ xs,
                                           const float* __restrict__ Wr,
                                           float* __restrict__ G) {
    __shared__ float xsl[64 * 64];
    __shared__ float wl[64 * 128];
    int kk = blockIdx.x, mt = blockIdx.y, b = blockIdx.z;
    int t = threadIdx.x;
    int to = t & 31, tmm = t >> 5;
    float acc[8][4] = {};
    for (int c0 = 0; c0 < NC; c0 += 64) {
        __syncthreads();
        #pragma unroll
        for (int it = 0; it < 16; ++it) {
            int f = it * 256 + t;
            int cc = f >> 6, mm = f & 63;
            xsl[f] = xs[((size_t)b * NC + c0 + cc) * NM + mt * 64 + mm];
        }
        #pragma unroll
        for (int it = 0; it < 32; ++it) {
            int f = it * 256 + t;
            int cc = f >> 7, o = f & 127;
            wl[f] = Wr[(size_t)(c0 + cc) * 1152 + kk * 128 + o];
        }
        __syncthreads();
        for (int cc = 0; cc < 64; ++cc) {
            const float4 a0 = *(const float4*)&xsl[cc * 64 + tmm * 8];
            const float4 a1 = *(const float4*)&xsl[cc * 64 + tmm * 8 + 4];
            float av[8] = {a0.x, a0.y, a0.z, a0.w, a1.x, a1.y, a1.z, a1.w};
            float2 w0 = *(const float2*)&wl[cc * 128 + 2 * to];
            float2 w1 = *(const float2*)&wl[cc * 128 + 64 + 2 * to];
            float wv[4] = {w0.x, w0.y, w1.x, w1.y};
            #pragma unroll
            for (int i = 0; i < 8; ++i)
                #pragma unroll
                for (int j = 0; j < 4; ++j)
                    acc[i][j] = fmaf(av[i], wv[j], acc[i][j]);
        }
    }
    #pragma unroll
    for (int i = 0; i < 8; ++i) {
        size_t base = (((size_t)(b * NM + mt * 64 + tmm * 8 + i) * NK + kk) << 7);
        *(float2*)&G[base + 2 * to]      = make_float2(acc[i][0], acc[i][1]);
        *(float2*)&G[base + 64 + 2 * to] = make_float2(acc[i][2], acc[i][3]);
    }
}

// ---------------------------------------------------------------------------
// K3 pass 1 (MFMA): split-bf16 dots + approx top-9 -> theta -> candidates.
// grid (64 token-tiles, 16 b), 256 thr (4 waves); block = 64 tokens x 256 samples.
// dot = xh*sh + xl*sh + xh*sl via 16x16x32 bf16 MFMA, K=128 per term.
__device__ inline unsigned long long shfl_xor_u64(unsigned long long v, int m) {
    int lo = __shfl_xor((int)(v & 0xFFFFFFFFull), m, 64);
    int hi = __shfl_xor((int)(v >> 32), m, 64);
    return ((unsigned long long)(unsigned)hi << 32) | (unsigned)lo;
}

#define STAGE_B(SRCP, KC) do {                                                  \
    __syncthreads();                                                            \
    _Pragma("unroll")                                                           \
    for (int it_ = 0; it_ < 8; ++it_) {                                         \
        int ch_ = it_ * 256 + t;                                                \
        int r_ = ch_ >> 3, g_ = ch_ & 7;                                        \
        uint4 v_ = *(const uint4*)&SRCP[((size_t)b * NM + r_) * NC + (KC) * 64 + g_ * 8]; \
        *(uint4*)&Bc[r_ * 64 + ((g_ ^ (r_ & 7)) * 8)] = v_;                     \
    }                                                                           \
    __syncthreads();                                                            \
} while (0)

#define MFMA_SEG(APTR, KC) do {                                                 \
    _Pragma("unroll")                                                           \
    for (int ks_ = 0; ks_ < 2; ++ks_) {                                         \
        bf16x8 af_[4], bg_[4];                                                  \
        int kga_ = (KC) * 8 + ks_ * 4 + quad;                                   \
        int kgb_ = ks_ * 4 + quad;                                              \
        _Pragma("unroll")                                                       \
        for (int i_ = 0; i_ < 4; ++i_)                                          \
            af_[i_] = *(const bf16x8*)&APTR[(16 * i_ + lr) * 128 + ((kga_ ^ (lr & 7)) * 8)]; \
        _Pragma("unroll")                                                       \
        for (int j_ = 0; j_ < 4; ++j_)                                          \
            bg_[j_] = *(const bf16x8*)&Bc[(64 * w + 16 * j_ + lr) * 64 + ((kgb_ ^ (lr & 7)) * 8)]; \
        _Pragma("unroll")                                                       \
        for (int i_ = 0; i_ < 4; ++i_)                                          \
            _Pragma("unroll")                                                   \
            for (int j_ = 0; j_ < 4; ++j_)                                      \
                acc[i_][j_] = __builtin_amdgcn_mfma_f32_16x16x32_bf16(          \
                    af_[i_], bg_[j_], acc[i_][j_], 0, 0, 0);                    \
    }                                                                           \
} while (0)

__global__ __launch_bounds__(256) void k_sel(const float* __restrict__ x,
                                             const unsigned short* __restrict__ xsTh,
                                             const unsigned short* __restrict__ xsTl,
                                             const float* __restrict__ m2,
                                             unsigned short* __restrict__ cand) {
    // regions: Ah @0 (16KB), Al @16384 (16KB), Bc/xstage @32768 (32KB)
    //          keysl f32[64][260] @0 (66560B) after compute
    __shared__ __align__(16) unsigned char smraw[66560];
    __shared__ float m2l[256];
    __shared__ int   cntl[64];
    unsigned short* Ah = (unsigned short*)smraw;
    unsigned short* Al = (unsigned short*)(smraw + 16384);
    unsigned short* Bc = (unsigned short*)(smraw + 32768);
    float* xstage = (float*)(smraw + 32768);
    float* keysl  = (float*)smraw;

    int b = blockIdx.y, n0 = blockIdx.x * 64;
    int t = threadIdx.x;
    int w = t >> 6, l = t & 63;
    int lr = l & 15, quad = l >> 4;
    m2l[t] = m2[b * NM + t];
    if (t < 64) cntl[t] = 0;

    // ---- stage A: x f32 tile [128c][64n] -> transpose + hi/lo split -> Ah/Al ----
    #pragma unroll
    for (int it = 0; it < 8; ++it) {                // 2048 float4
        int f4 = it * 256 + t;
        int cc = f4 >> 4, nn4 = (f4 & 15) * 4;
        *(float4*)&xstage[cc * 64 + nn4] =
            *(const float4*)&x[((size_t)b * NC + cc) * NN + n0 + nn4];
    }
    __syncthreads();
    {
        int r = t >> 2, q = t & 3;                  // token row, c-quarter
        #pragma unroll
        for (int g = 0; g < 4; ++g) {               // 4 groups of 8 c
            int cbase = q * 32 + g * 8;
            unsigned short h8[8], l8[8];
            #pragma unroll
            for (int e = 0; e < 8; ++e) {
                float v = xstage[(cbase + e) * 64 + r];
                unsigned short h = bf16_rne(v);
                float hf = __uint_as_float(((unsigned)h) << 16);
                h8[e] = h;
                l8[e] = bf16_rne(v - hf);
            }
            int gg = (q * 4 + g) ^ (r & 7);
            *(uint4*)&Ah[r * 128 + gg * 8] = *(uint4*)h8;
            *(uint4*)&Al[r * 128 + gg * 8] = *(uint4*)l8;
        }
    }

    f32x4 acc[4][4];
    #pragma unroll
    for (int i = 0; i < 4; ++i)
        #pragma unroll
        for (int j = 0; j < 4; ++j) acc[i][j] = (f32x4){0.f, 0.f, 0.f, 0.f};

    // ---- K loop: (Ah,Bh)+(Al,Bh) then (Ah,Bl), per k-half ----
    STAGE_B(xsTh, 0); MFMA_SEG(Ah, 0); MFMA_SEG(Al, 0);
    STAGE_B(xsTl, 0); MFMA_SEG(Ah, 0);
    STAGE_B(xsTh, 1); MFMA_SEG(Ah, 1); MFMA_SEG(Al, 1);
    STAGE_B(xsTl, 1); MFMA_SEG(Ah, 1);

    __syncthreads();
    // ---- phase B: keys = m2 - 2*dot from MFMA C-layout (col=lr, row=quad*4+r) ----
    #pragma unroll
    for (int i = 0; i < 4; ++i) {
        #pragma unroll
        for (int r = 0; r < 4; ++r) {
            int tok = 16 * i + quad * 4 + r;
            #pragma unroll
            for (int j = 0; j < 4; ++j) {
                int m = 64 * w + 16 * j + lr;
                keysl[tok * 260 + m] = fmaf(-2.f, acc[i][j][r], m2l[m]);
            }
        }
    }
    __syncthreads();
    // ---- phase C: approx top-9 (4 lanes/token) -> theta -> collect ----
    {
        int tok = t >> 2, q = t & 3;
        unsigned long long bk[9];
        #pragma unroll
        for (int j = 0; j < 9; ++j) bk[j] = ~0ull;
        for (int i = 0; i < 64; ++i) {
            int m = q + 4 * i;
            unsigned u = __float_as_uint(keysl[tok * 260 + m]);
            u = (u & 0x80000000u) ? ~u : (u | 0x80000000u);
            unsigned long long v = ((unsigned long long)u << 32) | (unsigned)m;
            if (v < bk[8]) {
                #pragma unroll
                for (int j = 0; j < 9; ++j) {
                    unsigned long long t0 = bk[j];
                    bool c = v < t0;
                    bk[j] = c ? v : t0;
                    v     = c ? t0 : v;
                }
            }
        }
        #pragma unroll
        for (int rr = 1; rr <= 2; rr <<= 1) {
            unsigned long long pv[9];
            #pragma unroll
            for (int j = 0; j < 9; ++j) pv[j] = shfl_xor_u64(bk[j], rr);
            #pragma unroll
            for (int j = 0; j < 9; ++j) {
                unsigned long long v = pv[j];
                if (v >= bk[8]) break;
                #pragma unroll
                for (int jj = 0; jj < 9; ++jj) {
                    unsigned long long t0 = bk[jj];
                    bool c = v < t0;
                    bk[jj] = c ? v : t0;
                    v      = c ? t0 : v;
                }
            }
        }
        unsigned u9 = (unsigned)(bk[8] >> 32);
        u9 = (u9 & 0x80000000u) ? (u9 & 0x7FFFFFFFu) : ~u9;
        float theta = __uint_as_float(u9) + DELTA;
        size_t tokbase = (size_t)(b * NN + n0 + tok) * 16;
        for (int i = 0; i < 64; ++i) {
            int m = q + 4 * i;
            if (keysl[tok * 260 + m] <= theta) {
                int pos = atomicAdd(&cntl[tok], 1);
                if (pos < 16) cand[tokbase + pos] = (unsigned short)m;
            }
        }
        __syncthreads();
        if (q == 0) {
            int c = cntl[tok]; if (c > 16) c = 16;
            for (int s = c; s < 16; ++s) cand[tokbase + s] = 0xFFFFu;
        }
    }
}

// ---------------------------------------------------------------------------
// K3 pass 2: np-bit-exact re-rank of <=16 candidates/token, reading xsT.
__global__ __launch_bounds__(256) void k_ref(const float* __restrict__ x,
                                             const float* __restrict__ xsT,
                                             const float* __restrict__ m2,
                                             const unsigned short* __restrict__ cand,
                                             int* __restrict__ idx) {
    #pragma clang fp contract(off)
    __shared__ float x1l[128 * 64];   // [c][r] 32 KB
    __shared__ float m2l[256];
    __shared__ unsigned long long pairs[64 * 16];   // 8 KB
    int b = blockIdx.y, n0 = blockIdx.x * 64;
    int t = threadIdx.x;
    m2l[t] = m2[b * NM + t];
    #pragma unroll
    for (int s = 0; s < 4; ++s) pairs[t * 4 + s] = ~0ull;
    #pragma unroll
    for (int it = 0; it < 8; ++it) {                // 2048 float4
        int f4 = it * 256 + t;
        int cc = f4 >> 4, nn4 = (f4 & 15) * 4;
        *(float4*)&x1l[cc * 64 + nn4] =
            *(const float4*)&x[((size_t)b * NC + cc) * NN + n0 + nn4];
    }
    __syncthreads();
    int r = t >> 2, q = t & 3;
    int n = n0 + r;
    size_t tokbase = (size_t)(b * NN + n) * 16;
    float n2 = 0.f;
    #pragma unroll 4
    for (int c = 0; c < NC; ++c) { float v = x1l[c * 64 + r]; n2 = __fadd_rn(n2, __fmul_rn(v, v)); }
    int   mym[4];
    #pragma unroll
    for (int s = 0; s < 4; ++s) {
        int m = cand[tokbase + q + 4 * s];
        mym[s] = m;
        if (m != 0xFFFF) {
            const float* xt = xsT + ((size_t)b * NM + m) * NC;
            float dot = 0.f;
            for (int c4 = 0; c4 < 32; ++c4) {       // sequential in-order: np order
                float4 sv = *(const float4*)&xt[4 * c4];
                dot = __fadd_rn(dot, __fmul_rn(x1l[(4 * c4 + 0) * 64 + r], sv.x));
                dot = __fadd_rn(dot, __fmul_rn(x1l[(4 * c4 + 1) * 64 + r], sv.y));
                dot = __fadd_rn(dot, __fmul_rn(x1l[(4 * c4 + 2) * 64 + r], sv.z));
                dot = __fadd_rn(dot, __fmul_rn(x1l[(4 * c4 + 3) * 64 + r], sv.w));
            }
            float key = __fsub_rn(__fadd_rn(n2, m2l[m]), __fmul_rn(2.f, dot));
            unsigned u = __float_as_uint(key);
            u = (u & 0x80000000u) ? ~u : (u | 0x80000000u);
            pairs[r * 16 + q * 4 + s] = ((unsigned long long)u << 32) | (unsigned)m;
        }
    }
    __syncthreads();
    unsigned long long pl[16];
    #pragma unroll
    for (int lx = 0; lx < 16; ++lx) pl[lx] = pairs[r * 16 + lx];
    size_t obase = (size_t)(b * NN + n) * NK;
    #pragma unroll
    for (int s = 0; s < 4; ++s) {
        if (mym[s] != 0xFFFF) {
            unsigned long long p = pairs[r * 16 + q * 4 + s];
            int rank = 0;
            #pragma unroll
            for (int lx = 0; lx < 16; ++lx) rank += (pl[lx] < p);
            if (rank < 9) idx[obase + rank] = mym[s];
        }
    }
}

// ---------------------------------------------------------------------------
// K4: out[b][o][n] = bias[o] + sum_k G[b][idx[b,n,k]][k][o]
__global__ __launch_bounds__(256) void k_out(const float* __restrict__ G,
                                             const int* __restrict__ idx,
                                             const float* __restrict__ bias,
                                             float* __restrict__ out) {
    __shared__ float S[64 * 129];
    __shared__ int   idxl[576];
    __shared__ float biasl[128];
    int b = blockIdx.y, n0 = blockIdx.x * 64;
    int t = threadIdx.x;
    if (t < 128) biasl[t] = bias[t];
    for (int f = t; f < 576; f += 256) idxl[f] = idx[(size_t)(b * NN + n0) * NK + f];
    __syncthreads();
    int o = t & 127, half = t >> 7;
    for (int p = 0; p < 32; ++p) {
        int n = p * 2 + half;
        float a = biasl[o];
        #pragma unroll
        for (int k = 0; k < 9; ++k) {
            int m = idxl[n * 9 + k];
            a += G[(((size_t)(b * NM + m)) * NK + k) * 128 + o];
        }
        S[n * 129 + o] = a;
    }
    __syncthreads();
    int nn = t & 63, ob = t >> 6;
    for (int p = 0; p < 32; ++p) {
        int o2 = p * 4 + ob;
        out[((size_t)(b * NO + o2)) * NN + n0 + nn] = S[nn * 129 + o2];
    }
}

// ---------------------------------------------------------------------------
extern "C" void kernel_launch(void* const* d_in, const int* in_sizes, int n_in,
                              void* d_out, int out_size, void* d_ws, size_t ws_size,
                              hipStream_t stream) {
    const float* x    = (const float*)d_in[0];   // (16,128,64,64)
    const float* w    = (const float*)d_in[1];   // (128,128,9)
    const float* bias = (const float*)d_in[2];   // (128,)
    float* out = (float*)d_out;

    float* ws   = (float*)d_ws;
    float* m2   = ws;                        // 4096
    float* xs   = ws + 4096;                 // 524288
    float* xsT  = ws + 528384;               // 524288
    float* Wr   = ws + 1052672;              // 147456
    float* G    = ws + 1200128;              // 4718592
    int*   idx  = (int*)(ws + 5918720);      // 589824
    unsigned short* cand = (unsigned short*)(ws + 6508544);  // 1048576 u16 = 524288 f
    unsigned short* xsTh = (unsigned short*)(ws + 7032832);  // 524288 u16 = 262144 f
    unsigned short* xsTl = (unsigned short*)(ws + 7294976);  // 524288 u16 = 262144 f
    // total ~30.2 MB

    k_wr    <<<dim3(576),       dim3(256), 0, stream>>>(w, Wr);
    k_gather<<<dim3(2048),      dim3(256), 0, stream>>>(x, xs);
    k_xt    <<<dim3(8, 16),     dim3(256), 0, stream>>>(xs, xsT, xsTh, xsTl);
    k_m2    <<<dim3(64),        dim3(64),  0, stream>>>(xsT, m2);
    k_g     <<<dim3(9, 4, 16),  dim3(256), 0, stream>>>(xs, Wr, G);
    k_sel   <<<dim3(64, 16),    dim3(256), 0, stream>>>(x, xsTh, xsTl, m2, cand);
    k_ref   <<<dim3(64, 16),    dim3(256), 0, stream>>>(x, xsT, m2, cand, idx);
    k_out   <<<dim3(64, 16),    dim3(256), 0, stream>>>(G, idx, bias, out);
}

// Round 7
// 236.465 us; speedup vs baseline: 1.3385x; 1.1527x over previous
//
#include <hip/hip_runtime.h>

// Problem constants (B=16, C=128, H=W=64, N=4096, M=256, K=9, OUT=128)
#define NB   16
#define NC   128
#define NN   4096
#define NM   256
#define NK   9
#define NO   128

#define DELTA 0.03f   // covers split-bf16 + fp32-accum key error (<=~1e-3) with big margin

typedef __attribute__((ext_vector_type(8))) short bf16x8;
typedef __attribute__((ext_vector_type(4))) float f32x4;

__device__ __constant__ int d_grid16[16] = {0,4,8,13,17,21,25,29,34,38,42,46,50,55,59,63};

__device__ inline unsigned short bf16_rne(float v) {
    unsigned u = __float_as_uint(v);
    return (unsigned short)((u + 0x7FFFu + ((u >> 16) & 1u)) >> 16);
}

// ---------------------------------------------------------------------------
// K_PREP: blocks [0,128): gather x samples -> xs, xsT, bf16 hi/lo planes.
//         blocks [128,704): w (O,C,K) -> Wr (C,K,O).
__global__ __launch_bounds__(256) void k_prep(const float* __restrict__ x,
                                              const float* __restrict__ w,
                                              float* __restrict__ xs,
                                              float* __restrict__ xsT,
                                              unsigned short* __restrict__ xsTh,
                                              unsigned short* __restrict__ xsTl,
                                              float* __restrict__ Wr) {
    __shared__ float tile[16 * 260];
    int bx = blockIdx.x, t = threadIdx.x;
    if (bx < 128) {
        int b = bx >> 3, c0 = (bx & 7) * 16;
        int m = t;
        int pix = d_grid16[m >> 4] * 64 + d_grid16[m & 15];
        #pragma unroll
        for (int cc = 0; cc < 16; ++cc) {
            float v = x[((size_t)b * NC + c0 + cc) * NN + pix];
            xs[((size_t)b * NC + c0 + cc) * NM + m] = v;
            tile[cc * 260 + m] = v;
        }
        __syncthreads();
        #pragma unroll
        for (int e = 0; e < 4; ++e) {
            float fv[4];
            fv[0] = tile[(4 * e + 0) * 260 + m];
            fv[1] = tile[(4 * e + 1) * 260 + m];
            fv[2] = tile[(4 * e + 2) * 260 + m];
            fv[3] = tile[(4 * e + 3) * 260 + m];
            size_t base = ((size_t)b * NM + m) * NC + c0 + 4 * e;
            *(float4*)&xsT[base] = make_float4(fv[0], fv[1], fv[2], fv[3]);
            unsigned short h4[4], l4[4];
            #pragma unroll
            for (int e2 = 0; e2 < 4; ++e2) {
                unsigned short h = bf16_rne(fv[e2]);
                h4[e2] = h;
                l4[e2] = bf16_rne(fv[e2] - __uint_as_float(((unsigned)h) << 16));
            }
            *(ushort4*)&xsTh[base] = make_ushort4(h4[0], h4[1], h4[2], h4[3]);
            *(ushort4*)&xsTl[base] = make_ushort4(l4[0], l4[1], l4[2], l4[3]);
        }
    } else {
        int f = (bx - 128) * 256 + t;               // < 147456
        int o = f & 127;
        int k = (f >> 7) % 9;
        int c = f / 1152;
        Wr[f] = w[o * 1152 + c * 9 + k];
    }
}

// ---------------------------------------------------------------------------
// K_G: z<16: G[b][m][k][o] = sum_c xs[b][c][m] * Wr[c][k][o] (fp32 fma).
//      z==16: m2[b][m] np-bit-exact (sequential c, mul+add, no fma).
__global__ __launch_bounds__(256) void k_g(const float* __restrict__ xs,
                                           const float* __restrict__ Wr,
                                           const float* __restrict__ xsT,
                                           float* __restrict__ G,
                                           float* __restrict__ m2) {
    __shared__ float xsl[64 * 64];
    __shared__ float wl[64 * 128];
    int t = threadIdx.x;
    if (blockIdx.z == 16) {
        #pragma clang fp contract(off)
        int fl = blockIdx.x * 4 + blockIdx.y;       // 0..35, use 0..15
        if (fl < 16) {
            const float* p = xsT + ((size_t)fl * NM + t) * NC;
            float a = 0.f;
            for (int c4 = 0; c4 < 32; ++c4) {
                float4 v = *(const float4*)&p[4 * c4];
                a = __fadd_rn(a, __fmul_rn(v.x, v.x));
                a = __fadd_rn(a, __fmul_rn(v.y, v.y));
                a = __fadd_rn(a, __fmul_rn(v.z, v.z));
                a = __fadd_rn(a, __fmul_rn(v.w, v.w));
            }
            m2[fl * NM + t] = a;
        }
        return;
    }
    int kk = blockIdx.x, mt = blockIdx.y, b = blockIdx.z;
    int to = t & 31, tmm = t >> 5;
    float acc[8][4] = {};
    for (int c0 = 0; c0 < NC; c0 += 64) {
        __syncthreads();
        #pragma unroll
        for (int it = 0; it < 16; ++it) {
            int f = it * 256 + t;
            int cc = f >> 6, mm = f & 63;
            xsl[f] = xs[((size_t)b * NC + c0 + cc) * NM + mt * 64 + mm];
        }
        #pragma unroll
        for (int it = 0; it < 32; ++it) {
            int f = it * 256 + t;
            int cc = f >> 7, o = f & 127;
            wl[f] = Wr[(size_t)(c0 + cc) * 1152 + kk * 128 + o];
        }
        __syncthreads();
        for (int cc = 0; cc < 64; ++cc) {
            const float4 a0 = *(const float4*)&xsl[cc * 64 + tmm * 8];
            const float4 a1 = *(const float4*)&xsl[cc * 64 + tmm * 8 + 4];
            float av[8] = {a0.x, a0.y, a0.z, a0.w, a1.x, a1.y, a1.z, a1.w};
            float2 w0 = *(const float2*)&wl[cc * 128 + 2 * to];
            float2 w1 = *(const float2*)&wl[cc * 128 + 64 + 2 * to];
            float wv[4] = {w0.x, w0.y, w1.x, w1.y};
            #pragma unroll
            for (int i = 0; i < 8; ++i)
                #pragma unroll
                for (int j = 0; j < 4; ++j)
                    acc[i][j] = fmaf(av[i], wv[j], acc[i][j]);
        }
    }
    #pragma unroll
    for (int i = 0; i < 8; ++i) {
        size_t base = (((size_t)(b * NM + mt * 64 + tmm * 8 + i) * NK + kk) << 7);
        *(float2*)&G[base + 2 * to]      = make_float2(acc[i][0], acc[i][1]);
        *(float2*)&G[base + 64 + 2 * to] = make_float2(acc[i][2], acc[i][3]);
    }
}

// ---------------------------------------------------------------------------
// K_SELREF: fused MFMA approx-dots -> theta -> candidates -> np-exact re-rank.
// grid (128, 16), 256 thr (4 waves); block = 32 tokens x 256 samples.
__global__ __launch_bounds__(256, 4) void k_selref(const float* __restrict__ x,
                                                   const unsigned short* __restrict__ xsTh,
                                                   const unsigned short* __restrict__ xsTl,
                                                   const float* __restrict__ xsT,
                                                   const float* __restrict__ m2,
                                                   int* __restrict__ idx) {
    #pragma clang fp contract(off)
    __shared__ float x1l[128 * 33];                 // f32 x tile [c][tok], np source
    __shared__ unsigned keysl[16 * 256];            // approx keys, one 16-token half
    __shared__ float m2l[256];
    __shared__ int cntl[32];
    __shared__ unsigned short candl[32 * 16];
    __shared__ unsigned long long pairs[32 * 17];
    int b = blockIdx.y, n0 = blockIdx.x * 32;
    int t = threadIdx.x;
    int w = t >> 6, lane = t & 63;
    int lr = lane & 15, quad = lane >> 4;
    m2l[t] = m2[b * NM + t];
    if (t < 32) cntl[t] = 0;
    // ---- stage x1l (f32, transposed; padded stride 33) ----
    #pragma unroll
    for (int it = 0; it < 4; ++it) {
        int f4 = it * 256 + t;
        int c = f4 >> 3, nn4 = (f4 & 7) * 4;
        float4 v = *(const float4*)&x[((size_t)b * NC + c) * NN + n0 + nn4];
        *(float4*)&x1l[c * 33 + nn4] = v;
    }
    __syncthreads();
    // ---- MFMA: dot = xh*sh + xl*sh + xh*sl ; A on-the-fly from x1l, B from global ----
    f32x4 acc[2][4];
    #pragma unroll
    for (int i = 0; i < 2; ++i)
        #pragma unroll
        for (int j = 0; j < 4; ++j) acc[i][j] = (f32x4){0.f, 0.f, 0.f, 0.f};
    for (int kb = 0; kb < 4; ++kb) {
        bf16x8 Ah[2], Al[2];
        #pragma unroll
        for (int i = 0; i < 2; ++i) {
            unsigned short h8[8], l8[8];
            #pragma unroll
            for (int e = 0; e < 8; ++e) {
                float v = x1l[(kb * 32 + quad * 8 + e) * 33 + 16 * i + lr];
                unsigned short h = bf16_rne(v);
                h8[e] = h;
                l8[e] = bf16_rne(v - __uint_as_float(((unsigned)h) << 16));
            }
            Ah[i] = *(bf16x8*)h8;
            Al[i] = *(bf16x8*)l8;
        }
        bf16x8 bh[4], bl[4];
        #pragma unroll
        for (int j = 0; j < 4; ++j)
            bh[j] = *(const bf16x8*)&xsTh[((size_t)b * NM + 64 * w + 16 * j + lr) * NC + kb * 32 + quad * 8];
        #pragma unroll
        for (int i = 0; i < 2; ++i)
            #pragma unroll
            for (int j = 0; j < 4; ++j)
                acc[i][j] = __builtin_amdgcn_mfma_f32_16x16x32_bf16(Ah[i], bh[j], acc[i][j], 0, 0, 0);
        #pragma unroll
        for (int i = 0; i < 2; ++i)
            #pragma unroll
            for (int j = 0; j < 4; ++j)
                acc[i][j] = __builtin_amdgcn_mfma_f32_16x16x32_bf16(Al[i], bh[j], acc[i][j], 0, 0, 0);
        #pragma unroll
        for (int j = 0; j < 4; ++j)
            bl[j] = *(const bf16x8*)&xsTl[((size_t)b * NM + 64 * w + 16 * j + lr) * NC + kb * 32 + quad * 8];
        #pragma unroll
        for (int i = 0; i < 2; ++i)
            #pragma unroll
            for (int j = 0; j < 4; ++j)
                acc[i][j] = __builtin_amdgcn_mfma_f32_16x16x32_bf16(Ah[i], bl[j], acc[i][j], 0, 0, 0);
    }
    // ---- two 16-token halves: keys -> theta -> candidate collect ----
    for (int h = 0; h < 2; ++h) {
        __syncthreads();
        // phase B: keys = m2 - 2*dot, monotone-u32, rotated columns (bank spread)
        #pragma unroll
        for (int r = 0; r < 4; ++r) {
            int tokL = 4 * quad + r;
            #pragma unroll
            for (int j = 0; j < 4; ++j) {
                int m = 64 * w + 16 * j + lr;
                float key = fmaf(-2.f, acc[h][j][r], m2l[m]);
                unsigned u = __float_as_uint(key);
                u = (u & 0x80000000u) ? ~u : (u | 0x80000000u);
                keysl[tokL * 256 + ((m + 8 * tokL) & 255)] = u;
            }
        }
        __syncthreads();
        // phase C: u32 top-9 (16 lanes/token x 16 keys) -> theta -> collect
        int tokL = t >> 4, q = t & 15;
        unsigned bk[9];
        #pragma unroll
        for (int j = 0; j < 9; ++j) bk[j] = 0xFFFFFFFFu;
        #pragma unroll
        for (int s = 0; s < 16; ++s) {
            int col = (16 * s + q + 8 * tokL) & 255;
            unsigned v = keysl[tokL * 256 + col];
            #pragma unroll
            for (int j = 0; j < 9; ++j) {
                unsigned mn = min(v, bk[j]);
                v = max(v, bk[j]);
                bk[j] = mn;
            }
        }
        #pragma unroll
        for (int d = 1; d <= 8; d <<= 1) {
            unsigned pv[9];
            #pragma unroll
            for (int j = 0; j < 9; ++j) pv[j] = (unsigned)__shfl_xor((int)bk[j], d, 64);
            #pragma unroll
            for (int j = 0; j < 9; ++j) {
                unsigned v = pv[j];
                if (v >= bk[8]) break;              // pv ascending
                #pragma unroll
                for (int jj = 0; jj < 9; ++jj) {
                    unsigned mn = min(v, bk[jj]);
                    v = max(v, bk[jj]);
                    bk[jj] = mn;
                }
            }
        }
        unsigned u9 = bk[8];
        unsigned ku = (u9 & 0x80000000u) ? (u9 & 0x7FFFFFFFu) : ~u9;
        float thf = __uint_as_float(ku) + DELTA;
        unsigned tu = __float_as_uint(thf);
        tu = (tu & 0x80000000u) ? ~tu : (tu | 0x80000000u);
        int tok = 16 * h + tokL;
        #pragma unroll
        for (int s = 0; s < 16; ++s) {
            int col = (16 * s + q + 8 * tokL) & 255;
            unsigned v = keysl[tokL * 256 + col];
            if (v <= tu) {
                int pos = atomicAdd(&cntl[tok], 1);
                if (pos < 16) candl[tok * 16 + pos] = (unsigned short)((col - 8 * tokL) & 255);
            }
        }
    }
    __syncthreads();
    if (t < 32) {
        int c = min(cntl[t], 16);
        for (int s = c; s < 16; ++s) candl[t * 16 + s] = 0xFFFFu;
    }
    __syncthreads();
    // ---- ref: np-bit-exact re-rank (32 tokens x 8 lanes x 2 slots) ----
    {
        int tok = t >> 3, q8 = t & 7;
        // exact n2: sequential c from x1l
        float n2 = 0.f;
        #pragma unroll 4
        for (int c = 0; c < NC; ++c) {
            float v = x1l[c * 33 + tok];
            n2 = __fadd_rn(n2, __fmul_rn(v, v));
        }
        int mym[2];
        unsigned long long myp[2];
        #pragma unroll
        for (int s = 0; s < 2; ++s) {
            int slot = q8 + 8 * s;
            int m = candl[tok * 16 + slot];
            mym[s] = m;
            unsigned long long p = ~0ull;
            if (m != 0xFFFF) {
                const float* xt = xsT + ((size_t)b * NM + m) * NC;
                float dot = 0.f;
                for (int c4 = 0; c4 < 32; ++c4) {
                    float4 sv = *(const float4*)&xt[4 * c4];
                    dot = __fadd_rn(dot, __fmul_rn(x1l[(4 * c4 + 0) * 33 + tok], sv.x));
                    dot = __fadd_rn(dot, __fmul_rn(x1l[(4 * c4 + 1) * 33 + tok], sv.y));
                    dot = __fadd_rn(dot, __fmul_rn(x1l[(4 * c4 + 2) * 33 + tok], sv.z));
                    dot = __fadd_rn(dot, __fmul_rn(x1l[(4 * c4 + 3) * 33 + tok], sv.w));
                }
                float key = __fsub_rn(__fadd_rn(n2, m2l[m]), __fmul_rn(2.f, dot));
                unsigned u = __float_as_uint(key);
                u = (u & 0x80000000u) ? ~u : (u | 0x80000000u);
                p = ((unsigned long long)u << 32) | (unsigned)m;
            }
            myp[s] = p;
            pairs[tok * 17 + slot] = p;
        }
        __syncthreads();
        unsigned long long pl[16];
        #pragma unroll
        for (int l2 = 0; l2 < 16; ++l2) pl[l2] = pairs[tok * 17 + l2];
        size_t obase = (size_t)(b * NN + n0 + tok) * NK;
        #pragma unroll
        for (int s = 0; s < 2; ++s) {
            if (mym[s] != 0xFFFF) {
                int rank = 0;
                #pragma unroll
                for (int l2 = 0; l2 < 16; ++l2) rank += (pl[l2] < myp[s]);
                if (rank < 9) idx[obase + rank] = mym[s];
            }
        }
    }
}

// ---------------------------------------------------------------------------
// K_OUT: out[b][o][n] = bias[o] + sum_k G[b][idx[b,n,k]][k][o]
__global__ __launch_bounds__(256) void k_out(const float* __restrict__ G,
                                             const int* __restrict__ idx,
                                             const float* __restrict__ bias,
                                             float* __restrict__ out) {
    __shared__ float S[64 * 129];
    __shared__ int   idxl[576];
    __shared__ float biasl[128];
    int b = blockIdx.y, n0 = blockIdx.x * 64;
    int t = threadIdx.x;
    if (t < 128) biasl[t] = bias[t];
    for (int f = t; f < 576; f += 256) idxl[f] = idx[(size_t)(b * NN + n0) * NK + f];
    __syncthreads();
    int o = t & 127, half = t >> 7;
    for (int p = 0; p < 32; ++p) {
        int n = p * 2 + half;
        float a = biasl[o];
        #pragma unroll
        for (int k = 0; k < 9; ++k) {
            int m = idxl[n * 9 + k];
            a += G[(((size_t)(b * NM + m)) * NK + k) * 128 + o];
        }
        S[n * 129 + o] = a;
    }
    __syncthreads();
    int nn = t & 63, ob = t >> 6;
    for (int p = 0; p < 32; ++p) {
        int o2 = p * 4 + ob;
        out[((size_t)(b * NO + o2)) * NN + n0 + nn] = S[nn * 129 + o2];
    }
}

// ---------------------------------------------------------------------------
extern "C" void kernel_launch(void* const* d_in, const int* in_sizes, int n_in,
                              void* d_out, int out_size, void* d_ws, size_t ws_size,
                              hipStream_t stream) {
    const float* x    = (const float*)d_in[0];   // (16,128,64,64)
    const float* w    = (const float*)d_in[1];   // (128,128,9)
    const float* bias = (const float*)d_in[2];   // (128,)
    float* out = (float*)d_out;

    float* ws   = (float*)d_ws;
    float* m2   = ws;                        // 4096
    float* xs   = ws + 4096;                 // 524288
    float* xsT  = ws + 528384;               // 524288
    float* Wr   = ws + 1052672;              // 147456
    float* G    = ws + 1200128;              // 4718592
    int*   idx  = (int*)(ws + 5918720);      // 589824
    unsigned short* xsTh = (unsigned short*)(ws + 6508544);  // 524288 u16
    unsigned short* xsTl = (unsigned short*)(ws + 6770688);  // 524288 u16
    // total ~28.1 MB

    k_prep  <<<dim3(704),       dim3(256), 0, stream>>>(x, w, xs, xsT, xsTh, xsTl, Wr);
    k_g     <<<dim3(9, 4, 17),  dim3(256), 0, stream>>>(xs, Wr, xsT, G, m2);
    k_selref<<<dim3(128, 16),   dim3(256), 0, stream>>>(x, xsTh, xsTl, xsT, m2, idx);
    k_out   <<<dim3(64, 16),    dim3(256), 0, stream>>>(G, idx, bias, out);
}

// Round 8
// 227.581 us; speedup vs baseline: 1.3907x; 1.0390x over previous
//
#include <hip/hip_runtime.h>

// Problem constants (B=16, C=128, H=W=64, N=4096, M=256, K=9, OUT=128)
#define NB   16
#define NC   128
#define NN   4096
#define NM   256
#define NK   9
#define NO   128

#define DELTA 0.03f   // covers split-bf16 + fp32-accum key error (<=~1e-3) with big margin

typedef __attribute__((ext_vector_type(8))) short bf16x8;
typedef __attribute__((ext_vector_type(4))) float f32x4;

__device__ __constant__ int d_grid16[16] = {0,4,8,13,17,21,25,29,34,38,42,46,50,55,59,63};

__device__ inline unsigned short bf16_rne(float v) {
    unsigned u = __float_as_uint(v);
    return (unsigned short)((u + 0x7FFFu + ((u >> 16) & 1u)) >> 16);
}

// ---------------------------------------------------------------------------
// K_PREP:
//   bx <  128 : gather samples -> xsT (f32 [b][m][c]) + bf16 hi/lo planes
//   bx <  704 : W (O,C,K) -> bf16 hi/lo planes Wt[(k*128+o)][c]
//   bx <  960 : n2[b][n] np-bit-exact (sequential c, mul+add)
//   bx < 976  : m2[b][m] np-bit-exact (gathers pixels directly from x)
__global__ __launch_bounds__(256) void k_prep(const float* __restrict__ x,
                                              const float* __restrict__ w,
                                              float* __restrict__ xsT,
                                              unsigned short* __restrict__ xsTh,
                                              unsigned short* __restrict__ xsTl,
                                              unsigned short* __restrict__ Wth,
                                              unsigned short* __restrict__ Wtl,
                                              float* __restrict__ n2g,
                                              float* __restrict__ m2) {
    __shared__ float tile[16 * 260];
    int bx = blockIdx.x, t = threadIdx.x;
    if (bx < 128) {
        int b = bx >> 3, c0 = (bx & 7) * 16;
        int m = t;
        int pix = d_grid16[m >> 4] * 64 + d_grid16[m & 15];
        #pragma unroll
        for (int cc = 0; cc < 16; ++cc)
            tile[cc * 260 + m] = x[((size_t)b * NC + c0 + cc) * NN + pix];
        __syncthreads();
        #pragma unroll
        for (int e = 0; e < 4; ++e) {
            float fv[4];
            fv[0] = tile[(4 * e + 0) * 260 + m];
            fv[1] = tile[(4 * e + 1) * 260 + m];
            fv[2] = tile[(4 * e + 2) * 260 + m];
            fv[3] = tile[(4 * e + 3) * 260 + m];
            size_t base = ((size_t)b * NM + m) * NC + c0 + 4 * e;
            *(float4*)&xsT[base] = make_float4(fv[0], fv[1], fv[2], fv[3]);
            unsigned short h4[4], l4[4];
            #pragma unroll
            for (int e2 = 0; e2 < 4; ++e2) {
                unsigned short h = bf16_rne(fv[e2]);
                h4[e2] = h;
                l4[e2] = bf16_rne(fv[e2] - __uint_as_float(((unsigned)h) << 16));
            }
            *(ushort4*)&xsTh[base] = make_ushort4(h4[0], h4[1], h4[2], h4[3]);
            *(ushort4*)&xsTl[base] = make_ushort4(l4[0], l4[1], l4[2], l4[3]);
        }
    } else if (bx < 704) {
        int f = (bx - 128) * 256 + t;               // < 147456 = 1152*128
        int ko = f >> 7, c = f & 127;
        int o = ko & 127, k = ko >> 7;
        float v = w[(size_t)o * 1152 + c * 9 + k];
        unsigned short h = bf16_rne(v);
        Wth[f] = h;
        Wtl[f] = bf16_rne(v - __uint_as_float(((unsigned)h) << 16));
    } else if (bx < 960) {
        #pragma clang fp contract(off)
        int i = bx - 704;                           // 256 blocks: b x 16 n-chunks
        int b = i >> 4, n = (i & 15) * 256 + t;
        const float* p = x + (size_t)b * NC * NN + n;
        float a = 0.f;
        #pragma unroll 4
        for (int c = 0; c < NC; ++c) { float v = p[(size_t)c * NN]; a = __fadd_rn(a, __fmul_rn(v, v)); }
        n2g[(size_t)b * NN + n] = a;
    } else {
        #pragma clang fp contract(off)
        int b = bx - 960;                           // 16 blocks: t = m
        int pix = d_grid16[t >> 4] * 64 + d_grid16[t & 15];
        const float* p = x + (size_t)b * NC * NN + pix;
        float a = 0.f;
        #pragma unroll 4
        for (int c = 0; c < NC; ++c) { float v = p[(size_t)c * NN]; a = __fadd_rn(a, __fmul_rn(v, v)); }
        m2[b * NM + t] = a;
    }
}

// ---------------------------------------------------------------------------
// K_G (MFMA): G[b][m][k][o] = sum_c xs[m][c] * W[k,o][c], split-bf16 3-term.
// 1-D grid 576 = 16 b (XCD-swizzled) x 9 k x 4 m-tiles; 256 thr (4 waves).
__global__ __launch_bounds__(256) void k_g(const unsigned short* __restrict__ xsTh,
                                           const unsigned short* __restrict__ xsTl,
                                           const unsigned short* __restrict__ Wth,
                                           const unsigned short* __restrict__ Wtl,
                                           float* __restrict__ G) {
    int id = blockIdx.x;
    int b = id & 15, r = id >> 4;                   // r < 36
    int kk = r % 9, mt = r / 9;
    int t = threadIdx.x;
    int w = t >> 6, lane = t & 63;
    int lr = lane & 15, quad = lane >> 4;
    int m = b * NM + mt * 64 + w * 16 + lr;
    const unsigned short* aph = xsTh + (size_t)m * NC;
    const unsigned short* apl = xsTl + (size_t)m * NC;
    f32x4 acc[8];
    #pragma unroll
    for (int j = 0; j < 8; ++j) acc[j] = (f32x4){0.f, 0.f, 0.f, 0.f};
    #pragma unroll
    for (int kb = 0; kb < 4; ++kb) {
        int co = kb * 32 + quad * 8;
        bf16x8 Ah = *(const bf16x8*)&aph[co];
        bf16x8 Al = *(const bf16x8*)&apl[co];
        #pragma unroll
        for (int j = 0; j < 8; ++j) {
            size_t wrow = ((size_t)kk * 128 + 16 * j + lr) * NC + co;
            bf16x8 Bh = *(const bf16x8*)&Wth[wrow];
            bf16x8 Bl = *(const bf16x8*)&Wtl[wrow];
            acc[j] = __builtin_amdgcn_mfma_f32_16x16x32_bf16(Ah, Bh, acc[j], 0, 0, 0);
            acc[j] = __builtin_amdgcn_mfma_f32_16x16x32_bf16(Al, Bh, acc[j], 0, 0, 0);
            acc[j] = __builtin_amdgcn_mfma_f32_16x16x32_bf16(Ah, Bl, acc[j], 0, 0, 0);
        }
    }
    int mrow = b * NM + mt * 64 + w * 16 + quad * 4;
    #pragma unroll
    for (int j = 0; j < 8; ++j)
        #pragma unroll
        for (int r2 = 0; r2 < 4; ++r2)
            G[((size_t)(mrow + r2)) * 1152 + kk * 128 + 16 * j + lr] = acc[j][r2];
}

// ---------------------------------------------------------------------------
// K_SELREF: MFMA approx dots -> theta -> candidates -> np-exact re-rank.
// 1-D grid 2048 = 16 b (XCD-swizzled) x 128 token-tiles; 256 thr; 32 tok x 256 m.
__global__ __launch_bounds__(256, 4) void k_selref(const float* __restrict__ x,
                                                   const unsigned short* __restrict__ xsTh,
                                                   const unsigned short* __restrict__ xsTl,
                                                   const float* __restrict__ xsT,
                                                   const float* __restrict__ m2,
                                                   const float* __restrict__ n2g,
                                                   int* __restrict__ idx) {
    #pragma clang fp contract(off)
    __shared__ __align__(16) float x1l[32 * 132];   // f32 x tile [tok][c], 16896 B
    __shared__ __align__(16) unsigned keysl[16 * 256]; // 16384 B; pairs aliases after use
    __shared__ float m2l[256];
    __shared__ float n2l[32];
    __shared__ int cntl[32];
    __shared__ unsigned short candl[32 * 16];
    unsigned long long* pairs = (unsigned long long*)keysl;   // 32*17*8 = 4352 <= 16384
    int b = blockIdx.x & 15, n0 = (blockIdx.x >> 4) * 32;
    int t = threadIdx.x;
    int w = t >> 6, lane = t & 63;
    int lr = lane & 15, quad = lane >> 4;
    m2l[t] = m2[b * NM + t];
    if (t < 32) { n2l[t] = n2g[(size_t)b * NN + n0 + t]; cntl[t] = 0; }
    // ---- stage x1l [tok][c] (transpose during write) ----
    #pragma unroll
    for (int it = 0; it < 4; ++it) {
        int f4 = it * 256 + t;
        int c = f4 >> 3, nn4 = (f4 & 7) * 4;
        float4 v = *(const float4*)&x[((size_t)b * NC + c) * NN + n0 + nn4];
        x1l[(nn4 + 0) * 132 + c] = v.x;
        x1l[(nn4 + 1) * 132 + c] = v.y;
        x1l[(nn4 + 2) * 132 + c] = v.z;
        x1l[(nn4 + 3) * 132 + c] = v.w;
    }
    __syncthreads();
    // ---- MFMA: dot = xh*sh + xl*sh + xh*sl ; A on-the-fly, B from global planes ----
    f32x4 acc[2][4];
    #pragma unroll
    for (int i = 0; i < 2; ++i)
        #pragma unroll
        for (int j = 0; j < 4; ++j) acc[i][j] = (f32x4){0.f, 0.f, 0.f, 0.f};
    for (int kb = 0; kb < 4; ++kb) {
        bf16x8 Ah[2], Al[2];
        #pragma unroll
        for (int i = 0; i < 2; ++i) {
            const float4 va = *(const float4*)&x1l[(16 * i + lr) * 132 + kb * 32 + quad * 8];
            const float4 vb = *(const float4*)&x1l[(16 * i + lr) * 132 + kb * 32 + quad * 8 + 4];
            float vf[8] = {va.x, va.y, va.z, va.w, vb.x, vb.y, vb.z, vb.w};
            unsigned short h8[8], l8[8];
            #pragma unroll
            for (int e = 0; e < 8; ++e) {
                unsigned short h = bf16_rne(vf[e]);
                h8[e] = h;
                l8[e] = bf16_rne(vf[e] - __uint_as_float(((unsigned)h) << 16));
            }
            Ah[i] = *(bf16x8*)h8;
            Al[i] = *(bf16x8*)l8;
        }
        bf16x8 bh[4], bl[4];
        #pragma unroll
        for (int j = 0; j < 4; ++j)
            bh[j] = *(const bf16x8*)&xsTh[((size_t)b * NM + 64 * w + 16 * j + lr) * NC + kb * 32 + quad * 8];
        #pragma unroll
        for (int i = 0; i < 2; ++i)
            #pragma unroll
            for (int j = 0; j < 4; ++j)
                acc[i][j] = __builtin_amdgcn_mfma_f32_16x16x32_bf16(Ah[i], bh[j], acc[i][j], 0, 0, 0);
        #pragma unroll
        for (int i = 0; i < 2; ++i)
            #pragma unroll
            for (int j = 0; j < 4; ++j)
                acc[i][j] = __builtin_amdgcn_mfma_f32_16x16x32_bf16(Al[i], bh[j], acc[i][j], 0, 0, 0);
        #pragma unroll
        for (int j = 0; j < 4; ++j)
            bl[j] = *(const bf16x8*)&xsTl[((size_t)b * NM + 64 * w + 16 * j + lr) * NC + kb * 32 + quad * 8];
        #pragma unroll
        for (int i = 0; i < 2; ++i)
            #pragma unroll
            for (int j = 0; j < 4; ++j)
                acc[i][j] = __builtin_amdgcn_mfma_f32_16x16x32_bf16(Ah[i], bl[j], acc[i][j], 0, 0, 0);
    }
    // ---- two 16-token halves: keys -> theta -> candidate collect ----
    for (int h = 0; h < 2; ++h) {
        __syncthreads();
        #pragma unroll
        for (int r = 0; r < 4; ++r) {
            int tokL = 4 * quad + r;
            #pragma unroll
            for (int j = 0; j < 4; ++j) {
                int m = 64 * w + 16 * j + lr;
                float key = fmaf(-2.f, acc[h][j][r], m2l[m]);
                unsigned u = __float_as_uint(key);
                u = (u & 0x80000000u) ? ~u : (u | 0x80000000u);
                keysl[tokL * 256 + ((m + 8 * tokL) & 255)] = u;
            }
        }
        __syncthreads();
        int tokL = t >> 4, q = t & 15;
        unsigned bk[9];
        #pragma unroll
        for (int j = 0; j < 9; ++j) bk[j] = 0xFFFFFFFFu;
        #pragma unroll
        for (int s = 0; s < 16; ++s) {
            int col = (16 * s + q + 8 * tokL) & 255;
            unsigned v = keysl[tokL * 256 + col];
            #pragma unroll
            for (int j = 0; j < 9; ++j) {
                unsigned mn = min(v, bk[j]);
                v = max(v, bk[j]);
                bk[j] = mn;
            }
        }
        #pragma unroll
        for (int d = 1; d <= 8; d <<= 1) {
            unsigned pv[9];
            #pragma unroll
            for (int j = 0; j < 9; ++j) pv[j] = (unsigned)__shfl_xor((int)bk[j], d, 64);
            #pragma unroll
            for (int j = 0; j < 9; ++j) {
                unsigned v = pv[j];
                if (v >= bk[8]) break;
                #pragma unroll
                for (int jj = 0; jj < 9; ++jj) {
                    unsigned mn = min(v, bk[jj]);
                    v = max(v, bk[jj]);
                    bk[jj] = mn;
                }
            }
        }
        unsigned u9 = bk[8];
        unsigned ku = (u9 & 0x80000000u) ? (u9 & 0x7FFFFFFFu) : ~u9;
        float thf = __uint_as_float(ku) + DELTA;
        unsigned tu = __float_as_uint(thf);
        tu = (tu & 0x80000000u) ? ~tu : (tu | 0x80000000u);
        int tok = 16 * h + tokL;
        #pragma unroll
        for (int s = 0; s < 16; ++s) {
            int col = (16 * s + q + 8 * tokL) & 255;
            unsigned v = keysl[tokL * 256 + col];
            if (v <= tu) {
                int pos = atomicAdd(&cntl[tok], 1);
                if (pos < 16) candl[tok * 16 + pos] = (unsigned short)((col - 8 * tokL) & 255);
            }
        }
    }
    __syncthreads();
    if (t < 32) {
        int c = min(cntl[t], 16);
        for (int s = c; s < 16; ++s) candl[t * 16 + s] = 0xFFFFu;
    }
    __syncthreads();
    // ---- ref: np-bit-exact re-rank (32 tokens x 8 lanes x 2 slots) ----
    {
        int tok = t >> 3, q8 = t & 7;
        float n2 = n2l[tok];
        int mym[2];
        unsigned long long myp[2];
        #pragma unroll
        for (int s = 0; s < 2; ++s) {
            int m = candl[tok * 16 + q8 + 8 * s];
            mym[s] = m;
            unsigned long long p = ~0ull;
            if (m != 0xFFFF) {
                const float* xt = xsT + ((size_t)b * NM + m) * NC;
                float dot = 0.f;
                for (int c4 = 0; c4 < 32; ++c4) {   // sequential in-order: np order
                    float4 xv = *(const float4*)&x1l[tok * 132 + 4 * c4];
                    float4 sv = *(const float4*)&xt[4 * c4];
                    dot = __fadd_rn(dot, __fmul_rn(xv.x, sv.x));
                    dot = __fadd_rn(dot, __fmul_rn(xv.y, sv.y));
                    dot = __fadd_rn(dot, __fmul_rn(xv.z, sv.z));
                    dot = __fadd_rn(dot, __fmul_rn(xv.w, sv.w));
                }
                float key = __fsub_rn(__fadd_rn(n2, m2l[m]), __fmul_rn(2.f, dot));
                unsigned u = __float_as_uint(key);
                u = (u & 0x80000000u) ? ~u : (u | 0x80000000u);
                p = ((unsigned long long)u << 32) | (unsigned)m;
            }
            myp[s] = p;
            pairs[tok * 17 + q8 + 8 * s] = p;
        }
        __syncthreads();
        unsigned long long pl[16];
        #pragma unroll
        for (int l2 = 0; l2 < 16; ++l2) pl[l2] = pairs[tok * 17 + l2];
        size_t obase = (size_t)(b * NN + n0 + tok) * NK;
        #pragma unroll
        for (int s = 0; s < 2; ++s) {
            if (mym[s] != 0xFFFF) {
                int rank = 0;
                #pragma unroll
                for (int l2 = 0; l2 < 16; ++l2) rank += (pl[l2] < myp[s]);
                if (rank < 9) idx[obase + rank] = mym[s];
            }
        }
    }
}

// ---------------------------------------------------------------------------
// K_OUT: out[b][o][n] = bias[o] + sum_k G[b][idx[b,n,k]][k][o]
// 1-D grid 1024 = 16 b (XCD-swizzled) x 64 token-tiles.
__global__ __launch_bounds__(256) void k_out(const float* __restrict__ G,
                                             const int* __restrict__ idx,
                                             const float* __restrict__ bias,
                                             float* __restrict__ out) {
    __shared__ float S[64 * 129];
    __shared__ int   idxl[576];
    __shared__ float biasl[128];
    int b = blockIdx.x & 15, n0 = (blockIdx.x >> 4) * 64;
    int t = threadIdx.x;
    if (t < 128) biasl[t] = bias[t];
    for (int f = t; f < 576; f += 256) idxl[f] = idx[(size_t)(b * NN + n0) * NK + f];
    __syncthreads();
    int o = t & 127, half = t >> 7;
    for (int p = 0; p < 32; ++p) {
        int n = p * 2 + half;
        float a = biasl[o];
        #pragma unroll
        for (int k = 0; k < 9; ++k) {
            int m = idxl[n * 9 + k];
            a += G[(((size_t)(b * NM + m)) * NK + k) * 128 + o];
        }
        S[n * 129 + o] = a;
    }
    __syncthreads();
    int nn = t & 63, ob = t >> 6;
    for (int p = 0; p < 32; ++p) {
        int o2 = p * 4 + ob;
        out[((size_t)(b * NO + o2)) * NN + n0 + nn] = S[nn * 129 + o2];
    }
}

// ---------------------------------------------------------------------------
extern "C" void kernel_launch(void* const* d_in, const int* in_sizes, int n_in,
                              void* d_out, int out_size, void* d_ws, size_t ws_size,
                              hipStream_t stream) {
    const float* x    = (const float*)d_in[0];   // (16,128,64,64)
    const float* w    = (const float*)d_in[1];   // (128,128,9)
    const float* bias = (const float*)d_in[2];   // (128,)
    float* out = (float*)d_out;

    float* ws   = (float*)d_ws;
    float* m2   = ws;                            // 4096
    float* n2g  = ws + 4096;                     // 65536
    float* xsT  = ws + 69632;                    // 524288
    float* G    = ws + 593920;                   // 4718592
    int*   idx  = (int*)(ws + 5312512);          // 589824
    unsigned short* xsTh = (unsigned short*)(ws + 5902336);  // 524288 u16
    unsigned short* xsTl = (unsigned short*)(ws + 6164480);  // 524288 u16
    unsigned short* Wth  = (unsigned short*)(ws + 6426624);  // 147456 u16
    unsigned short* Wtl  = (unsigned short*)(ws + 6500352);  // 147456 u16
    // total 6574080 floats ~= 26.3 MB

    k_prep  <<<dim3(976),  dim3(256), 0, stream>>>(x, w, xsT, xsTh, xsTl, Wth, Wtl, n2g, m2);
    k_g     <<<dim3(576),  dim3(256), 0, stream>>>(xsTh, xsTl, Wth, Wtl, G);
    k_selref<<<dim3(2048), dim3(256), 0, stream>>>(x, xsTh, xsTl, xsT, m2, n2g, idx);
    k_out   <<<dim3(1024), dim3(256), 0, stream>>>(G, idx, bias, out);
}